// Round 1
// baseline (130.125 us; speedup 1.0000x reference)
//
#include <hip/hip_runtime.h>
#include <hip/hip_bf16.h>

#define B_ 8
#define S_ 2048
#define E_ 1024
#define H_ 64

typedef __attribute__((ext_vector_type(8))) short short8;
typedef __attribute__((ext_vector_type(4))) float f32x4;

__device__ __forceinline__ unsigned short f2bf(float f) {
    unsigned int u = __float_as_uint(f);
    u = (u + 0x7FFFu + ((u >> 16) & 1u)) >> 16;
    return (unsigned short)u;
}

// Kernel 0: Wq/Wk/Wv [1024][64] f32 -> Wt bf16 [192][1024] (transposed, n-major)
__global__ __launch_bounds__(256) void prep_weights(
    const float* __restrict__ Wq, const float* __restrict__ Wk,
    const float* __restrict__ Wv, unsigned short* __restrict__ Wt)
{
    int idx = blockIdx.x * 256 + threadIdx.x;  // 192*1024 total
    int n = idx >> 10, k = idx & (E_ - 1);
    const float* W = (n < 64) ? Wq : (n < 128) ? Wk : Wv;
    int h = n & 63;
    Wt[idx] = f2bf(W[k * 64 + h]);
}

// Kernel 1: QKV projection. 1 wave = 16 rows x 192 cols, MFMA over K=1024.
// Writes Q,K bf16 [B*S][64] and V transposed Vt bf16 [B][64][S].
__global__ __launch_bounds__(256) void qkv_proj(
    const float* __restrict__ x, const float* __restrict__ bq,
    const float* __restrict__ bk, const float* __restrict__ bv,
    const unsigned short* __restrict__ Wt,
    unsigned short* __restrict__ Q, unsigned short* __restrict__ K,
    unsigned short* __restrict__ Vt)
{
    int tid = threadIdx.x;
    int wave = tid >> 6, lane = tid & 63;
    int lo = lane & 15, hi = lane >> 4;
    int rowbase = (blockIdx.x * 4 + wave) * 16;

    f32x4 acc[12];
    #pragma unroll
    for (int i = 0; i < 12; ++i) acc[i] = (f32x4){0.f, 0.f, 0.f, 0.f};

    const float* xr = x + (size_t)(rowbase + lo) * E_ + 8 * hi;
    const unsigned short* wp = Wt + (size_t)lo * E_ + 8 * hi;
    for (int k0 = 0; k0 < E_; k0 += 32) {
        float4 a0 = *(const float4*)(xr + k0);
        float4 a1 = *(const float4*)(xr + k0 + 4);
        short8 af;
        af[0] = f2bf(a0.x); af[1] = f2bf(a0.y); af[2] = f2bf(a0.z); af[3] = f2bf(a0.w);
        af[4] = f2bf(a1.x); af[5] = f2bf(a1.y); af[6] = f2bf(a1.z); af[7] = f2bf(a1.w);
        #pragma unroll
        for (int nt = 0; nt < 12; ++nt) {
            short8 bf = *(const short8*)(wp + (size_t)nt * 16 * E_ + k0);
            acc[nt] = __builtin_amdgcn_mfma_f32_16x16x32_bf16(af, bf, acc[nt], 0, 0, 0);
        }
    }

    #pragma unroll
    for (int nt = 0; nt < 12; ++nt) {
        int n = nt * 16 + lo;
        #pragma unroll
        for (int r = 0; r < 4; ++r) {
            int row = rowbase + 4 * hi + r;   // global row in [0, 16384)
            float v = acc[nt][r];
            if (nt < 4) {
                Q[(size_t)row * 64 + n] = f2bf(v + bq[n]);
            } else if (nt < 8) {
                int h = n - 64;
                K[(size_t)row * 64 + h] = f2bf(v + bk[h]);
            } else {
                int h = n - 128;
                int b = row >> 11, s = row & (S_ - 1);
                Vt[((size_t)b * 64 + h) * S_ + s] = f2bf(v + bv[h]);
            }
        }
    }
}

// Kernel 2: flash attention. Block = 2 waves (128 thr), QT=32 (16 rows/wave), KT=64.
__global__ __launch_bounds__(128) void attn(
    const unsigned short* __restrict__ Q, const unsigned short* __restrict__ K,
    const unsigned short* __restrict__ Vt, const int* __restrict__ mask,
    float* __restrict__ out)
{
    __shared__ __align__(16) unsigned short p_lds[2][16][72]; // +8 pad vs 64
    int tid = threadIdx.x;
    int wave = tid >> 6, lane = tid & 63;
    int lo = lane & 15, hi = lane >> 4;
    int b = blockIdx.y;
    int qt = 63 - blockIdx.x;          // heavy (large qt) blocks first
    int qrow0 = qt * 32 + wave * 16;

    const unsigned short* qp = Q + ((size_t)(b * S_ + qrow0 + lo)) * 64 + 8 * hi;
    short8 qf0 = *(const short8*)(qp);
    short8 qf1 = *(const short8*)(qp + 32);

    f32x4 o[4];
    float m[4], ls[4];
    #pragma unroll
    for (int i = 0; i < 4; ++i) {
        o[i] = (f32x4){0.f, 0.f, 0.f, 0.f};
        m[i] = -__builtin_inff();
        ls[i] = 0.f;
    }

    int ktmax = (qt * 32 + 31) >> 6;
    for (int kt = 0; kt <= ktmax; ++kt) {
        int kbase = kt * 64;
        f32x4 s[4];
        #pragma unroll
        for (int i = 0; i < 4; ++i) s[i] = (f32x4){0.f, 0.f, 0.f, 0.f};

        // S = Q K^T (per wave: 16 q-rows x 64 k-pos)
        const unsigned short* kp = K + ((size_t)(b * S_ + kbase + lo)) * 64 + 8 * hi;
        #pragma unroll
        for (int nt = 0; nt < 4; ++nt) {
            short8 kf0 = *(const short8*)(kp + (size_t)nt * 16 * 64);
            short8 kf1 = *(const short8*)(kp + (size_t)nt * 16 * 64 + 32);
            s[nt] = __builtin_amdgcn_mfma_f32_16x16x32_bf16(qf0, kf0, s[nt], 0, 0, 0);
            s[nt] = __builtin_amdgcn_mfma_f32_16x16x32_bf16(qf1, kf1, s[nt], 0, 0, 0);
        }

        // masking (causal + pad), scale 1/sqrt(64)
        int mv[4];
        #pragma unroll
        for (int nt = 0; nt < 4; ++nt) mv[nt] = mask[b * S_ + kbase + nt * 16 + lo];
        float rmax[4];
        #pragma unroll
        for (int r = 0; r < 4; ++r) rmax[r] = -__builtin_inff();
        #pragma unroll
        for (int nt = 0; nt < 4; ++nt) {
            int kpos = kbase + nt * 16 + lo;
            #pragma unroll
            for (int r = 0; r < 4; ++r) {
                int qpos = qrow0 + 4 * hi + r;
                float v = s[nt][r] * 0.125f;
                bool ok = (mv[nt] != 0) && (kpos <= qpos);
                v = ok ? v : -__builtin_inff();
                s[nt][r] = v;
                rmax[r] = fmaxf(rmax[r], v);
            }
        }
        #pragma unroll
        for (int r = 0; r < 4; ++r) {
            rmax[r] = fmaxf(rmax[r], __shfl_xor(rmax[r], 1));
            rmax[r] = fmaxf(rmax[r], __shfl_xor(rmax[r], 2));
            rmax[r] = fmaxf(rmax[r], __shfl_xor(rmax[r], 4));
            rmax[r] = fmaxf(rmax[r], __shfl_xor(rmax[r], 8));
        }
        float mneff[4], sc[4];
        #pragma unroll
        for (int r = 0; r < 4; ++r) {
            float mn = fmaxf(m[r], rmax[r]);
            bool dead = (mn == -__builtin_inff());
            mneff[r] = dead ? 0.f : mn;
            sc[r] = __expf(m[r] - mneff[r]);
            m[r] = dead ? m[r] : mn;
        }
        float ps[4] = {0.f, 0.f, 0.f, 0.f};
        #pragma unroll
        for (int nt = 0; nt < 4; ++nt) {
            #pragma unroll
            for (int r = 0; r < 4; ++r) {
                float p = __expf(s[nt][r] - mneff[r]);
                ps[r] += p;
                p_lds[wave][4 * hi + r][nt * 16 + lo] = f2bf(p);
            }
        }
        #pragma unroll
        for (int r = 0; r < 4; ++r) {
            ps[r] += __shfl_xor(ps[r], 1);
            ps[r] += __shfl_xor(ps[r], 2);
            ps[r] += __shfl_xor(ps[r], 4);
            ps[r] += __shfl_xor(ps[r], 8);
            ls[r] = ls[r] * sc[r] + ps[r];
        }
        #pragma unroll
        for (int nt = 0; nt < 4; ++nt) {
            #pragma unroll
            for (int r = 0; r < 4; ++r) o[nt][r] *= sc[r];
        }

        // O += P V  (P via LDS round-trip to A-layout; V from transposed Vt)
        const unsigned short* vp = Vt + (size_t)b * 64 * S_ + kbase;
        #pragma unroll
        for (int kk = 0; kk < 2; ++kk) {
            short8 pf = *(const short8*)&p_lds[wave][lo][kk * 32 + 8 * hi];
            #pragma unroll
            for (int nt = 0; nt < 4; ++nt) {
                short8 vf = *(const short8*)(vp + (size_t)(nt * 16 + lo) * S_ + kk * 32 + 8 * hi);
                o[nt] = __builtin_amdgcn_mfma_f32_16x16x32_bf16(pf, vf, o[nt], 0, 0, 0);
            }
        }
    }

    #pragma unroll
    for (int nt = 0; nt < 4; ++nt) {
        #pragma unroll
        for (int r = 0; r < 4; ++r) {
            int qpos = qrow0 + 4 * hi + r;
            out[((size_t)(b * S_ + qpos)) * 64 + nt * 16 + lo] = o[nt][r] / ls[r];
        }
    }
}

extern "C" void kernel_launch(void* const* d_in, const int* in_sizes, int n_in,
                              void* d_out, int out_size, void* d_ws, size_t ws_size,
                              hipStream_t stream) {
    const float* x   = (const float*)d_in[0];
    const int*   msk = (const int*)d_in[1];
    const float* Wq  = (const float*)d_in[2];
    const float* bq  = (const float*)d_in[3];
    const float* Wk  = (const float*)d_in[4];
    const float* bk  = (const float*)d_in[5];
    const float* Wv  = (const float*)d_in[6];
    const float* bv  = (const float*)d_in[7];
    float* out = (float*)d_out;

    // ws layout: Wt bf16 384KB @0 | Q bf16 2MB @512KB | K bf16 2MB | Vt bf16 2MB  (6.5MB total)
    unsigned short* Wt = (unsigned short*)d_ws;
    unsigned short* Qb = (unsigned short*)((char*)d_ws + (1u << 19));
    unsigned short* Kb = (unsigned short*)((char*)d_ws + (1u << 19) + (1u << 21));
    unsigned short* Vt = (unsigned short*)((char*)d_ws + (1u << 19) + (2u << 21));

    prep_weights<<<dim3(768), dim3(256), 0, stream>>>(Wq, Wk, Wv, Wt);
    qkv_proj<<<dim3(256), dim3(256), 0, stream>>>(x, bq, bk, bv, Wt, Qb, Kb, Vt);
    attn<<<dim3(64, 8), dim3(128), 0, stream>>>(Qb, Kb, Vt, msk, out);
}